// Round 1
// baseline (865.600 us; speedup 1.0000x reference)
//
#include <hip/hip_runtime.h>
#include <math.h>

// Problem constants (from reference)
#define N_TOK 8192
#define DIM   4096
#define NEXP  64
#define CAP   160                        // ceil(1.25*8192/64)
#define OFF_CW    (83886080ULL)          // N_TOK*NEXP*CAP
#define OFF_PROBS (167772160ULL)
#define OFF_LOSS  (168296448ULL)         // OFF_PROBS + N_TOK*NEXP
#define NA    16384                      // N_TOK * K
#define SPLIT 8                          // D-split for GEMM

typedef float vfloat4 __attribute__((ext_vector_type(4)));   // nt-store compatible

// ---------------- wave (64-lane) reductions ----------------
__device__ __forceinline__ float wave_max64(float v) {
    for (int m = 1; m < 64; m <<= 1) v = fmaxf(v, __shfl_xor(v, m, 64));
    return v;
}
__device__ __forceinline__ float wave_sum64(float v) {
    for (int m = 1; m < 64; m <<= 1) v += __shfl_xor(v, m, 64);
    return v;
}
// argmax with tie-break to LOWEST index (matches lax.top_k stability)
__device__ __forceinline__ void wave_argmax64(float& v, int& i) {
    for (int m = 1; m < 64; m <<= 1) {
        float ov = __shfl_xor(v, m, 64);
        int   oi = __shfl_xor(i, m, 64);
        if (ov > v || (ov == v && oi < i)) { v = ov; i = oi; }
    }
}

// ---------------- K1: logits GEMM (standalone) ----------------
// 1024 blocks: (bx = id&127, by = id>>7) computes 64 tokens x 64 experts
// partial dot over D-slice by (512 wide). 4x4 register tile, LDS staging.
// 34.8KB LDS + ~90 VGPR -> 4 blocks/CU: all 1024 blocks co-resident at once;
// staging/compute overlap comes from the 4 desynced blocks per CU.
__global__ __launch_bounds__(256) void k_gemm(const float* __restrict__ x,
                                              const float* __restrict__ gw,
                                              float* __restrict__ part) {
    __shared__ float xs[64][68];   // +4 pad: breaks pow2 bank stride, keeps 16B align
    __shared__ float wsh[64][68];
    const int tb = (blockIdx.x & 127) * 64;
    const int sy = blockIdx.x >> 7;              // D-slice index 0..7
    const int d_begin = sy * (DIM / SPLIT);
    const int t  = threadIdx.x;
    const int tx = t & 15, ty = t >> 4;
    float acc[4][4] = {};
    for (int ci = 0; ci < (DIM / SPLIT) / 64; ++ci) {
        const int d0 = d_begin + ci * 64;
        for (int it = 0; it < 4; ++it) {
            int idx = t + 256 * it;        // 0..1023
            int row = idx >> 4;            // 0..63
            int d4  = idx & 15;
            *(float4*)(&xs[row][4 * d4]) =
                *(const float4*)(x + (size_t)(tb + row) * DIM + d0 + 4 * d4);
            *(float4*)(&wsh[row][4 * d4]) =
                *(const float4*)(gw + (size_t)row * DIM + d0 + 4 * d4);
        }
        __syncthreads();
        for (int d4 = 0; d4 < 16; ++d4) {
            float4 xa[4], wb[4];
            for (int i = 0; i < 4; ++i) xa[i] = *(const float4*)(&xs[ty + 16 * i][4 * d4]);
            for (int j = 0; j < 4; ++j) wb[j] = *(const float4*)(&wsh[tx + 16 * j][4 * d4]);
            for (int i = 0; i < 4; ++i)
                for (int j = 0; j < 4; ++j) {
                    acc[i][j] = fmaf(xa[i].x, wb[j].x, acc[i][j]);
                    acc[i][j] = fmaf(xa[i].y, wb[j].y, acc[i][j]);
                    acc[i][j] = fmaf(xa[i].z, wb[j].z, acc[i][j]);
                    acc[i][j] = fmaf(xa[i].w, wb[j].w, acc[i][j]);
                }
        }
        __syncthreads();
    }
    for (int i = 0; i < 4; ++i)
        for (int j = 0; j < 4; ++j)
            part[(size_t)sy * N_TOK * NEXP +
                 (size_t)(tb + ty + 16 * i) * NEXP + (tx + 16 * j)] = acc[i][j];
}

// ---------------- K2: softmax + top-2 per token (wave per token) ----------------
__global__ __launch_bounds__(256) void k_router(const float* __restrict__ part,
                                                float* __restrict__ probs_out,
                                                int* __restrict__ rec_e,
                                                float* __restrict__ rec_w) {
    const int tok  = blockIdx.x * 4 + (threadIdx.x >> 6);
    const int lane = threadIdx.x & 63;
    float l = 0.f;
    for (int s = 0; s < SPLIT; ++s)
        l += part[(size_t)s * N_TOK * NEXP + (size_t)tok * NEXP + lane];
    const float m  = wave_max64(l);
    const float ex = expf(l - m);
    const float sm = wave_sum64(ex);
    const float p  = ex / sm;
    probs_out[(size_t)tok * NEXP + lane] = p;
    float v1 = p; int i1 = lane;
    wave_argmax64(v1, i1);
    float v2 = (lane == i1) ? -1.f : p; int i2 = lane;
    wave_argmax64(v2, i2);
    if (lane == 0) {
        const float denom = v1 + v2;
        rec_e[2 * tok]     = i1;
        rec_e[2 * tok + 1] = i2;
        rec_w[2 * tok]     = v1 / denom;
        rec_w[2 * tok + 1] = v2 / denom;
    }
}

// ---------------- K3: probs partial column sums (deterministic, no atomics) ----
// 64 blocks x 256. Block b sums tokens [b*128, b*128+128) -> psum_part[b][64].
__global__ __launch_bounds__(256) void k_preduce(const float* __restrict__ probs,
                                                 float* __restrict__ psum_part) {
    __shared__ float sh[256];
    const int e = threadIdx.x & 63, tg = threadIdx.x >> 6;
    const int tok0 = blockIdx.x * 128;
    float a = 0.f;
    for (int k = 0; k < 32; ++k)
        a += probs[(size_t)(tok0 + tg + 4 * k) * NEXP + e];
    sh[threadIdx.x] = a;
    __syncthreads();
    if (threadIdx.x < 64)
        psum_part[blockIdx.x * 64 + threadIdx.x] =
            sh[threadIdx.x] + sh[64 + threadIdx.x] +
            sh[128 + threadIdx.x] + sh[192 + threadIdx.x];
}

// ---------------- K4: capacity slot assignment + loss ----------------
// Blocks 0..15 (64 waves): wave w owns expert w; scans the 16384 flat
// assignments in token-major order (matching the reference cumsum) in 256
// ballot rounds; exact exclusive prefix count per expert -> rec_s.
// Block 16: recomputes per-expert totals via LDS int histogram (exact, no
// cross-block dependency) and emits the load-balance loss.
__global__ __launch_bounds__(256) void k_assign(const int* __restrict__ rec_e,
                                                int* __restrict__ rec_s,
                                                const float* __restrict__ psum_part,
                                                float* __restrict__ out) {
    if (blockIdx.x == 16) {
        __shared__ int hcnt[64];
        if (threadIdx.x < 64) hcnt[threadIdx.x] = 0;
        __syncthreads();
        for (int j = 0; j < 64; ++j) {
            const int e = rec_e[j * 256 + threadIdx.x];
            atomicAdd(&hcnt[e], 1);
        }
        __syncthreads();
        if (threadIdx.x < 64) {
            const int e = threadIdx.x;
            float ps = 0.f;
            for (int b = 0; b < 64; ++b) ps += psum_part[b * 64 + e];
            float term = ((float)hcnt[e] / (float)NA) * (ps / (float)N_TOK);
            term = wave_sum64(term);
            if (e == 0) out[OFF_LOSS] = 0.01f * 64.f * term;
        }
        return;
    }
    const int w    = blockIdx.x * 4 + (threadIdx.x >> 6);   // expert id
    const int lane = threadIdx.x & 63;
    int base = 0;
    const unsigned long long ltmask = (1ull << lane) - 1ull;
    #pragma unroll 4
    for (int c = 0; c < NA / 64; ++c) {
        const int i = c * 64 + lane;
        const int e = rec_e[i];
        const unsigned long long mask = __ballot(e == w);
        if (e == w) {
            const int slot = base + __popcll(mask & ltmask);
            rec_s[i] = (slot < CAP) ? slot : -1;
        }
        base += __popcll(mask);
    }
}

// ---------------- K5: fused zero + scatter stream ----------------
// 2048 blocks x 4 tokens. Streams the full 64x160 dm+cw slab of each token
// with nt-stores; the token's <=2 kept assignments are patched into the
// stream branchlessly (compile-time vector-lane indices, so no scratch and
// no store-ordering hazard). Tiny footprint (no LDS, ~20 VGPR) -> fill-like
// occupancy; the harness fill shows this saturates write BW (6.4 TB/s).
__global__ __launch_bounds__(256) void k_zero_scatter(const int* __restrict__ rec_e,
                                                      const int* __restrict__ rec_s,
                                                      const float* __restrict__ rec_w,
                                                      float* __restrict__ out) {
    const int t = threadIdx.x;
    for (int tk = 0; tk < 4; ++tk) {
        const int tok = blockIdx.x * 4 + tk;
        const int e0 = rec_e[2 * tok],     e1 = rec_e[2 * tok + 1];
        const int s0 = rec_s[2 * tok],     s1 = rec_s[2 * tok + 1];
        const float w0 = rec_w[2 * tok],   w1 = rec_w[2 * tok + 1];
        const int p0 = (s0 >= 0) ? e0 * CAP + s0 : -1;   // flat pos in 10240 slab
        const int p1 = (s1 >= 0) ? e1 * CAP + s1 : -1;
        float* dm = out + (size_t)tok * (NEXP * CAP);
        float* cw = out + OFF_CW + (size_t)tok * (NEXP * CAP);
        for (int it = 0; it < 10; ++it) {
            const int b4 = 4 * (it * 256 + t);
            vfloat4 zd = {0.f, 0.f, 0.f, 0.f};
            vfloat4 zc = {0.f, 0.f, 0.f, 0.f};
            #pragma unroll
            for (int j = 0; j < 4; ++j) {              // j is compile-time
                const int pos = b4 + j;
                if (pos == p0) { zd[j] = 1.0f; zc[j] = w0; }
                if (pos == p1) { zd[j] = 1.0f; zc[j] = w1; }
            }
            __builtin_nontemporal_store(zd, (vfloat4*)(dm + b4));
            __builtin_nontemporal_store(zc, (vfloat4*)(cw + b4));
        }
    }
}

extern "C" void kernel_launch(void* const* d_in, const int* in_sizes, int n_in,
                              void* d_out, int out_size, void* d_ws, size_t ws_size,
                              hipStream_t stream) {
    const float* x  = (const float*)d_in[0];
    const float* gw = (const float*)d_in[1];
    float* out = (float*)d_out;

    char* w = (char*)d_ws;
    float* part      = (float*)w;                                      // SPLIT*8192*64
    int*   rec_e     = (int*)(w + (size_t)SPLIT * N_TOK * NEXP * 4);
    float* rec_w     = (float*)((char*)rec_e + NA * 4);
    int*   rec_s     = (int*)((char*)rec_w + NA * 4);
    float* psum_part = (float*)((char*)rec_s + NA * 4);

    k_gemm<<<1024, 256, 0, stream>>>(x, gw, part);
    k_router<<<2048, 256, 0, stream>>>(part, out + OFF_PROBS, rec_e, rec_w);
    k_preduce<<<64, 256, 0, stream>>>(out + OFF_PROBS, psum_part);
    k_assign<<<17, 256, 0, stream>>>(rec_e, rec_s, psum_part, out);
    k_zero_scatter<<<2048, 256, 0, stream>>>(rec_e, rec_s, rec_w, out);
}

// Round 2
// 763.244 us; speedup vs baseline: 1.1341x; 1.1341x over previous
//
#include <hip/hip_runtime.h>
#include <math.h>

// Problem constants (from reference)
#define N_TOK 8192
#define DIM   4096
#define NEXP  64
#define CAP   160                        // ceil(1.25*8192/64)
#define OFF_CW    (83886080ULL)          // N_TOK*NEXP*CAP (floats)
#define OFF_PROBS (167772160ULL)
#define OFF_LOSS  (168296448ULL)         // OFF_PROBS + N_TOK*NEXP
#define NA    16384                      // N_TOK * K
#define SPLIT 8                          // D-split for GEMM

typedef float vfloat4 __attribute__((ext_vector_type(4)));   // nt-store compatible

// ---------------- wave (64-lane) reductions ----------------
__device__ __forceinline__ float wave_max64(float v) {
    for (int m = 1; m < 64; m <<= 1) v = fmaxf(v, __shfl_xor(v, m, 64));
    return v;
}
__device__ __forceinline__ float wave_sum64(float v) {
    for (int m = 1; m < 64; m <<= 1) v += __shfl_xor(v, m, 64);
    return v;
}
// argmax with tie-break to LOWEST index (matches lax.top_k stability)
__device__ __forceinline__ void wave_argmax64(float& v, int& i) {
    for (int m = 1; m < 64; m <<= 1) {
        float ov = __shfl_xor(v, m, 64);
        int   oi = __shfl_xor(i, m, 64);
        if (ov > v || (ov == v && oi < i)) { v = ov; i = oi; }
    }
}

// ---------------- K1: GEMM with zero-stream woven into the K-loop ----------------
// 1024 blocks: (bx = id&127, by = id>>7) computes 64 tokens x 64 experts partial
// dot over D-slice by (512 wide). 4x4 register tile, LDS staging.
// Zero-stream: the 671 MB dm+cw region is treated as one flat range; block b owns
// float4s [b*40960, (b+1)*40960). Each ci-step nt-stores 5 float4/thread (40
// total = 2560 B/thread). Stores are fire-and-forget and drain on the otherwise
// idle HBM write channel while the LDS/VALU-bound FMA loop runs -> K1 ~=
// max(compute ~85us, HBM 142MB read + 688MB write ~132us) instead of their sum.
__global__ __launch_bounds__(256) void k_gemm_zero(const float* __restrict__ x,
                                                   const float* __restrict__ gw,
                                                   float* __restrict__ part,
                                                   float* __restrict__ out) {
    __shared__ float xs[64][68];   // +4 pad: breaks pow2 bank stride, keeps 16B align
    __shared__ float wsh[64][68];
    const int tb = (blockIdx.x & 127) * 64;
    const int sy = blockIdx.x >> 7;              // D-slice index 0..7
    const int d_begin = sy * (DIM / SPLIT);
    const int t  = threadIdx.x;
    const int tx = t & 15, ty = t >> 4;
    float* zbase = out + (size_t)blockIdx.x * 163840;   // this block's 40960 float4s
    const vfloat4 z = {0.f, 0.f, 0.f, 0.f};
    float acc[4][4] = {};
    for (int ci = 0; ci < (DIM / SPLIT) / 64; ++ci) {   // 8 iterations
        const int d0 = d_begin + ci * 64;
        for (int it = 0; it < 4; ++it) {
            int idx = t + 256 * it;        // 0..1023
            int row = idx >> 4;            // 0..63
            int d4  = idx & 15;
            *(float4*)(&xs[row][4 * d4]) =
                *(const float4*)(x + (size_t)(tb + row) * DIM + d0 + 4 * d4);
            *(float4*)(&wsh[row][4 * d4]) =
                *(const float4*)(gw + (size_t)row * DIM + d0 + 4 * d4);
        }
        // interleaved zero-stream: 5 float4 nt-stores per thread per ci-step
        #pragma unroll
        for (int zi = 0; zi < 5; ++zi)
            __builtin_nontemporal_store(
                z, (vfloat4*)(zbase + 4 * ((ci * 5 + zi) * 256 + t)));
        __syncthreads();
        for (int d4 = 0; d4 < 16; ++d4) {
            float4 xa[4], wb[4];
            for (int i = 0; i < 4; ++i) xa[i] = *(const float4*)(&xs[ty + 16 * i][4 * d4]);
            for (int j = 0; j < 4; ++j) wb[j] = *(const float4*)(&wsh[tx + 16 * j][4 * d4]);
            for (int i = 0; i < 4; ++i)
                for (int j = 0; j < 4; ++j) {
                    acc[i][j] = fmaf(xa[i].x, wb[j].x, acc[i][j]);
                    acc[i][j] = fmaf(xa[i].y, wb[j].y, acc[i][j]);
                    acc[i][j] = fmaf(xa[i].z, wb[j].z, acc[i][j]);
                    acc[i][j] = fmaf(xa[i].w, wb[j].w, acc[i][j]);
                }
        }
        __syncthreads();
    }
    for (int i = 0; i < 4; ++i)
        for (int j = 0; j < 4; ++j)
            part[(size_t)sy * N_TOK * NEXP +
                 (size_t)(tb + ty + 16 * i) * NEXP + (tx + 16 * j)] = acc[i][j];
}

// ---------------- K2: softmax + top-2 per token (wave per token) ----------------
__global__ __launch_bounds__(256) void k_router(const float* __restrict__ part,
                                                float* __restrict__ probs_out,
                                                int* __restrict__ rec_e,
                                                float* __restrict__ rec_w) {
    const int tok  = blockIdx.x * 4 + (threadIdx.x >> 6);
    const int lane = threadIdx.x & 63;
    float l = 0.f;
    for (int s = 0; s < SPLIT; ++s)
        l += part[(size_t)s * N_TOK * NEXP + (size_t)tok * NEXP + lane];
    const float m  = wave_max64(l);
    const float ex = expf(l - m);
    const float sm = wave_sum64(ex);
    const float p  = ex / sm;
    probs_out[(size_t)tok * NEXP + lane] = p;
    float v1 = p; int i1 = lane;
    wave_argmax64(v1, i1);
    float v2 = (lane == i1) ? -1.f : p; int i2 = lane;
    wave_argmax64(v2, i2);
    if (lane == 0) {
        const float denom = v1 + v2;
        rec_e[2 * tok]     = i1;
        rec_e[2 * tok + 1] = i2;
        rec_w[2 * tok]     = v1 / denom;
        rec_w[2 * tok + 1] = v2 / denom;
    }
}

// ---------------- K3: probs partial column sums (deterministic, no atomics) ----
// 64 blocks x 256. Block b sums tokens [b*128, b*128+128) -> psum_part[b][64].
__global__ __launch_bounds__(256) void k_preduce(const float* __restrict__ probs,
                                                 float* __restrict__ psum_part) {
    __shared__ float sh[256];
    const int e = threadIdx.x & 63, tg = threadIdx.x >> 6;
    const int tok0 = blockIdx.x * 128;
    float a = 0.f;
    for (int k = 0; k < 32; ++k)
        a += probs[(size_t)(tok0 + tg + 4 * k) * NEXP + e];
    sh[threadIdx.x] = a;
    __syncthreads();
    if (threadIdx.x < 64)
        psum_part[blockIdx.x * 64 + threadIdx.x] =
            sh[threadIdx.x] + sh[64 + threadIdx.x] +
            sh[128 + threadIdx.x] + sh[192 + threadIdx.x];
}

// ---------------- K4: slot assignment + inline scatter + loss ----------------
// Blocks 0..15 (64 waves): wave w owns expert w; scans the 16384 flat
// assignments in token-major order (matching the reference cumsum) in 256
// ballot rounds. Kept assignments are written straight into the pre-zeroed
// output (unique (tok,e,slot) per expert -> no collisions); no rec_s buffer,
// no separate scatter kernel. Block 16: per-expert totals via LDS histogram
// (exact, no cross-block dependency) + load-balance loss.
__global__ __launch_bounds__(256) void k_assign_scatter(const int* __restrict__ rec_e,
                                                        const float* __restrict__ rec_w,
                                                        const float* __restrict__ psum_part,
                                                        float* __restrict__ out) {
    if (blockIdx.x == 16) {
        __shared__ int hcnt[64];
        if (threadIdx.x < 64) hcnt[threadIdx.x] = 0;
        __syncthreads();
        for (int j = 0; j < 64; ++j) {
            const int e = rec_e[j * 256 + threadIdx.x];
            atomicAdd(&hcnt[e], 1);
        }
        __syncthreads();
        if (threadIdx.x < 64) {
            const int e = threadIdx.x;
            float ps = 0.f;
            for (int b = 0; b < 64; ++b) ps += psum_part[b * 64 + e];
            float term = ((float)hcnt[e] / (float)NA) * (ps / (float)N_TOK);
            term = wave_sum64(term);
            if (e == 0) out[OFF_LOSS] = 0.01f * 64.f * term;
        }
        return;
    }
    const int w    = blockIdx.x * 4 + (threadIdx.x >> 6);   // expert id
    const int lane = threadIdx.x & 63;
    int base = 0;
    const unsigned long long ltmask = (1ull << lane) - 1ull;
    #pragma unroll 4
    for (int c = 0; c < NA / 64; ++c) {
        const int i = c * 64 + lane;
        const int e = rec_e[i];
        const unsigned long long mask = __ballot(e == w);
        if (e == w) {
            const int slot = base + __popcll(mask & ltmask);
            if (slot < CAP) {
                const int tok = i >> 1;
                const size_t off = (size_t)tok * (NEXP * CAP) + (size_t)w * CAP + slot;
                out[off]          = 1.0f;
                out[OFF_CW + off] = rec_w[i];
            }
        }
        base += __popcll(mask);
    }
}

extern "C" void kernel_launch(void* const* d_in, const int* in_sizes, int n_in,
                              void* d_out, int out_size, void* d_ws, size_t ws_size,
                              hipStream_t stream) {
    const float* x  = (const float*)d_in[0];
    const float* gw = (const float*)d_in[1];
    float* out = (float*)d_out;

    char* w = (char*)d_ws;
    float* part      = (float*)w;                                      // SPLIT*8192*64
    int*   rec_e     = (int*)(w + (size_t)SPLIT * N_TOK * NEXP * 4);
    float* rec_w     = (float*)((char*)rec_e + NA * 4);
    float* psum_part = (float*)((char*)rec_w + NA * 4);

    k_gemm_zero<<<1024, 256, 0, stream>>>(x, gw, part, out);
    k_router<<<2048, 256, 0, stream>>>(part, out + OFF_PROBS, rec_e, rec_w);
    k_preduce<<<64, 256, 0, stream>>>(out + OFF_PROBS, psum_part);
    k_assign_scatter<<<17, 256, 0, stream>>>(rec_e, rec_w, psum_part, out);
}